// Round 7
// baseline (760.366 us; speedup 1.0000x reference)
//
#include <hip/hip_runtime.h>

#define DFEAT 64
#define BKSZ 256            // nodes per bucket
#define SB 8                // log2(BKSZ)
#define MAXBKT 512          // scan width; requires nbkt <= 512
#define PLACE_CHUNK 8192

typedef __attribute__((ext_vector_type(8))) short bf16x8;
typedef __attribute__((ext_vector_type(4))) float f32x4;

__device__ inline unsigned short f2bf(float f) {
  unsigned int x = __float_as_uint(f);
  return (unsigned short)((x + 0x7fffu + ((x >> 16) & 1u)) >> 16);
}

// ===========================================================================
// K1: fp32->bf16 conversion (feat + sentinel zero row + W) AND bucket hist.
// ===========================================================================
__global__ __launch_bounds__(256) void gcn_prep(
    const float4* __restrict__ feat4, ushort4* __restrict__ gb4, int n4,
    const float4* __restrict__ w4, ushort4* __restrict__ wb4, int nw4,
    const int* __restrict__ dst, int* __restrict__ bcnt,
    int n_edges, int nbkt) {
  int total = n4 + 16 + nw4;
  for (int i = blockIdx.x * 256 + threadIdx.x; i < total; i += gridDim.x * 256) {
    if (i < n4) {
      float4 f = feat4[i];
      ushort4 u;
      u.x = f2bf(f.x); u.y = f2bf(f.y); u.z = f2bf(f.z); u.w = f2bf(f.w);
      gb4[i] = u;
    } else if (i < n4 + 16) {
      gb4[i] = (ushort4){0, 0, 0, 0};          // sentinel row (node n_nodes)
    } else {
      float4 f = w4[i - n4 - 16];
      ushort4 u;
      u.x = f2bf(f.x); u.y = f2bf(f.y); u.z = f2bf(f.z); u.w = f2bf(f.w);
      wb4[i - n4 - 16] = u;
    }
  }
  __shared__ int h[MAXBKT];
  for (int i = threadIdx.x; i < nbkt; i += 256) h[i] = 0;
  __syncthreads();
  int ne4 = n_edges >> 2;
  const int4* d4 = (const int4*)dst;
  for (int e = blockIdx.x * 256 + threadIdx.x; e < ne4; e += gridDim.x * 256) {
    int4 v = d4[e];
    atomicAdd(&h[v.x >> SB], 1);
    atomicAdd(&h[v.y >> SB], 1);
    atomicAdd(&h[v.z >> SB], 1);
    atomicAdd(&h[v.w >> SB], 1);
  }
  if (blockIdx.x == 0)
    for (int e = (ne4 << 2) + threadIdx.x; e < n_edges; e += 256)
      atomicAdd(&h[dst[e] >> SB], 1);
  __syncthreads();
  for (int i = threadIdx.x; i < nbkt; i += 256)
    if (h[i]) atomicAdd(&bcnt[i], h[i]);
}

// ===========================================================================
// K2: exclusive scan of bucket counts -> bbase[0..nbkt].
// ===========================================================================
__global__ __launch_bounds__(MAXBKT) void gcn_bscan(
    const int* __restrict__ bcnt, int* __restrict__ bbase, int nbkt) {
  __shared__ int buf[2][MAXBKT];
  int t = threadIdx.x;
  buf[0][t] = (t < nbkt) ? bcnt[t] : 0;
  __syncthreads();
  int pin = 0;
  for (int s = 1; s < MAXBKT; s <<= 1) {
    int po = pin ^ 1;
    int v = buf[pin][t];
    if (t >= s) v += buf[pin][t - s];
    buf[po][t] = v;
    __syncthreads();
    pin = po;
  }
  if (t < nbkt) {
    bbase[t] = (t == 0) ? 0 : buf[pin][t - 1];
    if (t == nbkt - 1) bbase[nbkt] = buf[pin][t];
  }
}

// ===========================================================================
// K3: group edges by bucket as packed u32 (src | local<<24).
// ===========================================================================
__global__ __launch_bounds__(512) void gcn_place(
    const int* __restrict__ src, const int* __restrict__ dst,
    const int* __restrict__ bbase, int* __restrict__ bcur,
    unsigned int* __restrict__ pairs, int n_edges, int nbkt) {
  __shared__ int cnt[MAXBKT];
  __shared__ int base[MAXBKT];
  int t = threadIdx.x;
  cnt[t] = 0;
  __syncthreads();
  int e0 = blockIdx.x * PLACE_CHUNK;
  int e1 = min(e0 + PLACE_CHUNK, n_edges);
  for (int e = e0 + t; e < e1; e += 512) atomicAdd(&cnt[dst[e] >> SB], 1);
  __syncthreads();
  if (t < nbkt) {
    int c = cnt[t];
    base[t] = bbase[t] + (c ? atomicAdd(&bcur[t], c) : 0);
    cnt[t] = 0;   // reuse as local cursor
  }
  __syncthreads();
  for (int e = e0 + t; e < e1; e += 512) {
    int d = dst[e];
    int b = d >> SB;
    int pos = base[b] + atomicAdd(&cnt[b], 1);
    pairs[pos] = (unsigned)src[e] | ((unsigned)(d & (BKSZ - 1)) << 24);
  }
}

// ===========================================================================
// K4: fused bucket-LDS aggregation + concat + MFMA Linear.
// One block (512 thr = 8 waves) per 256-node bucket.
//
// Accumulate: edges stream coalesced from pairs; per wave-step 2 edges
// (lanes 0-31 / 32-63), each lane loads ushort2 (2 bf16 dims) of its edge's
// feat row and ds_add_f32's into acc[local][dim] (LDS atomics; rows padded
// to 68 floats for aligned b128 reads later).  Sentinel pairs (src=N zero
// row, local=0) make masked lanes add 0.0 -- no tails, no divergence.
//
// MFMA epilogue: per wave 2 tiles of 16 nodes.  A-frag feat half read
// straight from global bf16 table; agg half read from LDS f32 + cvt.
// W in registers as B-frags.  C/D: col=lane&15, row=(lane>>4)*4+reg.
// ===========================================================================
__global__ __launch_bounds__(512, 4) void gcn_agg_mfma(
    const unsigned short* __restrict__ gb,   // [N+1][64] bf16, row N zeros
    const unsigned short* __restrict__ wb,   // [64][128] bf16 W
    const unsigned int* __restrict__ pairs,
    const int* __restrict__ bbase,
    const float* __restrict__ bias,
    float* __restrict__ out,
    int n_nodes) {
  __shared__ float acc[BKSZ][68];            // 69632 B -> 2 blocks/CU
  int tid = threadIdx.x;
  int wave = tid >> 6, lane = tid & 63;
  int b = blockIdx.x;
  int n0 = b << SB;
  int e0 = bbase[b], e1 = bbase[b + 1];

  for (int i = tid; i < BKSZ * 68; i += 512) ((float*)acc)[i] = 0.f;
  __syncthreads();

  // ---- accumulate ----
  int h = lane >> 5;                 // which of 2 edges in this step
  int kk = lane & 31;                // ushort2 index within feat row
  unsigned SENTP = (unsigned)n_nodes;   // src = zero row, local = 0
  for (int base = e0 + wave * 64; base < e1; base += 512) {
    int rem = e1 - base;
    unsigned id = (lane < rem) ? pairs[base + lane] : SENTP;
    int lim = min(64, rem);
#pragma unroll 4
    for (int j = 0; j < lim; j += 2) {
      unsigned p = __shfl(id, j + h);
      int s = (int)(p & 0xFFFFFFu);
      int loc = (int)(p >> 24);
      unsigned int w = *(const unsigned int*)(gb + s * 64 + kk * 2);
      atomicAdd(&acc[loc][kk * 2 + 0], __uint_as_float(w << 16));
      atomicAdd(&acc[loc][kk * 2 + 1], __uint_as_float(w & 0xffff0000u));
    }
  }
  __syncthreads();

  // ---- MFMA epilogue ----
  int lrow = lane & 15, lkg = lane >> 4;
  bf16x8 wf[4][4];
#pragma unroll
  for (int kt = 0; kt < 4; ++kt)
#pragma unroll
    for (int jt = 0; jt < 4; ++jt)
      wf[kt][jt] =
          *(const bf16x8*)(wb + (jt * 16 + lrow) * 128 + kt * 32 + lkg * 8);

  float bj[4];
#pragma unroll
  for (int jt = 0; jt < 4; ++jt) bj[jt] = bias[jt * 16 + lrow];

#pragma unroll
  for (int ti = 0; ti < 2; ++ti) {
    int tile = wave * 2 + ti;
    int nrow = n0 + tile * 16 + lrow;
    int nload = (nrow < n_nodes) ? nrow : n_nodes;   // sentinel row if OOB

    f32x4 cacc[4];
#pragma unroll
    for (int jt = 0; jt < 4; ++jt) cacc[jt] = (f32x4){0.f, 0.f, 0.f, 0.f};

#pragma unroll
    for (int kt = 0; kt < 2; ++kt) {   // feat half from global bf16 table
      bf16x8 af = *(const bf16x8*)(gb + nload * 64 + kt * 32 + lkg * 8);
#pragma unroll
      for (int jt = 0; jt < 4; ++jt)
        cacc[jt] = __builtin_amdgcn_mfma_f32_16x16x32_bf16(af, wf[kt][jt],
                                                           cacc[jt], 0, 0, 0);
    }
#pragma unroll
    for (int kt = 2; kt < 4; ++kt) {   // agg half from LDS f32
      const float* ap = &acc[tile * 16 + lrow][(kt - 2) * 32 + lkg * 8];
      float4 lo = *(const float4*)ap;
      float4 hi = *(const float4*)(ap + 4);
      bf16x8 af;
      af[0] = (short)f2bf(lo.x); af[1] = (short)f2bf(lo.y);
      af[2] = (short)f2bf(lo.z); af[3] = (short)f2bf(lo.w);
      af[4] = (short)f2bf(hi.x); af[5] = (short)f2bf(hi.y);
      af[6] = (short)f2bf(hi.z); af[7] = (short)f2bf(hi.w);
#pragma unroll
      for (int jt = 0; jt < 4; ++jt)
        cacc[jt] = __builtin_amdgcn_mfma_f32_16x16x32_bf16(af, wf[kt][jt],
                                                           cacc[jt], 0, 0, 0);
    }

#pragma unroll
    for (int jt = 0; jt < 4; ++jt) {
#pragma unroll
      for (int r = 0; r < 4; ++r) {
        int n = n0 + tile * 16 + lkg * 4 + r;
        if (n < n_nodes) out[n * DFEAT + jt * 16 + lrow] = cacc[jt][r] + bj[jt];
      }
    }
  }
}

// ===========================================================================
// Last-resort fallback: atomic scatter + separate vector GEMM.
// ===========================================================================
__global__ __launch_bounds__(256) void gcn_scatter_kernel(
    const float4* __restrict__ feat4, const int* __restrict__ src,
    const int* __restrict__ dst, float* __restrict__ agg, int n_edges) {
  long long gid = (long long)blockIdx.x * blockDim.x + threadIdx.x;
  int e = (int)(gid >> 4);
  int c = (int)(gid & 15);
  if (e >= n_edges) return;
  float4 v = feat4[src[e] * 16 + c];
  float* p = agg + dst[e] * DFEAT + c * 4;
  atomicAdd(p + 0, v.x);
  atomicAdd(p + 1, v.y);
  atomicAdd(p + 2, v.z);
  atomicAdd(p + 3, v.w);
}

__global__ __launch_bounds__(256) void gcn_gemm_kernel(
    const float* __restrict__ feat, const float* __restrict__ agg,
    const float* __restrict__ W, const float* __restrict__ bias,
    float* __restrict__ out, int n_nodes) {
  __shared__ float4 Wl4[2048];
  __shared__ __align__(16) float hlf[16][128];
  int tid = threadIdx.x;
  for (int i = tid; i < 2048; i += 256) {
    int j = i >> 5, k4 = i & 31;
    Wl4[k4 * 64 + (j ^ (k4 & 7))] = ((const float4*)W)[i];
  }
  int node0 = blockIdx.x * 16;
  int wave = tid >> 6, lane = tid & 63;
  int mbase = wave * 4;
#pragma unroll
  for (int r = 0; r < 4; ++r) {
    int n = node0 + mbase + r;
    if (n < n_nodes) {
      hlf[mbase + r][lane]      = feat[n * DFEAT + lane];
      hlf[mbase + r][64 + lane] = agg[n * DFEAT + lane];
    }
  }
  __syncthreads();
  float a0 = 0.f, a1 = 0.f, a2 = 0.f, a3 = 0.f;
#pragma unroll 4
  for (int k4 = 0; k4 < 32; ++k4) {
    float4 w  = Wl4[k4 * 64 + (lane ^ (k4 & 7))];
    float4 h0 = *((const float4*)&hlf[mbase + 0][k4 * 4]);
    float4 h1 = *((const float4*)&hlf[mbase + 1][k4 * 4]);
    float4 h2 = *((const float4*)&hlf[mbase + 2][k4 * 4]);
    float4 h3 = *((const float4*)&hlf[mbase + 3][k4 * 4]);
    a0 += w.x * h0.x + w.y * h0.y + w.z * h0.z + w.w * h0.w;
    a1 += w.x * h1.x + w.y * h1.y + w.z * h1.z + w.w * h1.w;
    a2 += w.x * h2.x + w.y * h2.y + w.z * h2.z + w.w * h2.w;
    a3 += w.x * h3.x + w.y * h3.y + w.z * h3.z + w.w * h3.w;
  }
  float bj = bias[lane];
  int n = node0 + mbase;
  if (n + 0 < n_nodes) out[(n + 0) * DFEAT + lane] = a0 + bj;
  if (n + 1 < n_nodes) out[(n + 1) * DFEAT + lane] = a1 + bj;
  if (n + 2 < n_nodes) out[(n + 2) * DFEAT + lane] = a2 + bj;
  if (n + 3 < n_nodes) out[(n + 3) * DFEAT + lane] = a3 + bj;
}

// ===========================================================================

extern "C" void kernel_launch(void* const* d_in, const int* in_sizes, int n_in,
                              void* d_out, int out_size, void* d_ws, size_t ws_size,
                              hipStream_t stream) {
  const float* feat = (const float*)d_in[0];
  const int*   src  = (const int*)d_in[1];
  const int*   dst  = (const int*)d_in[2];
  const float* W    = (const float*)d_in[3];
  const float* bias = (const float*)d_in[4];
  float* out = (float*)d_out;

  int n_nodes = in_sizes[0] / DFEAT;   // 100000
  int n_edges = in_sizes[1];           // 1600000
  int nbkt = (n_nodes + BKSZ - 1) >> SB;   // 391

  auto align_up = [](size_t x) { return (x + 255) & ~(size_t)255; };
  size_t pair_b = align_up((size_t)n_edges * 4);
  size_t bcnt_b = align_up((size_t)MAXBKT * 4);
  size_t bcur_b = align_up((size_t)MAXBKT * 4);
  size_t bbas_b = align_up((size_t)(MAXBKT + 1) * 4);
  size_t wb_b   = align_up((size_t)DFEAT * 128 * 2);
  size_t gb_b   = align_up((size_t)(n_nodes + 1) * DFEAT * 2);  // +sentinel
  size_t need   = pair_b + bcnt_b + bcur_b + bbas_b + wb_b + gb_b;

  bool ok = nbkt >= 1 && nbkt <= MAXBKT && ws_size >= need;

  if (ok) {
    char* p = (char*)d_ws;
    unsigned int* pairs = (unsigned int*)p;    p += pair_b;
    int* bcnt  = (int*)p;                      p += bcnt_b;
    int* bcur  = (int*)p;                      p += bcur_b;
    int* bbase = (int*)p;                      p += bbas_b;
    unsigned short* wb = (unsigned short*)p;   p += wb_b;
    unsigned short* gb = (unsigned short*)p;

    hipMemsetAsync(bcnt, 0, bcnt_b + bcur_b, stream);   // bcnt + bcur

    int n4 = n_nodes * (DFEAT / 4);
    int nw4 = DFEAT * 128 / 4;
    gcn_prep<<<1024, 256, 0, stream>>>(
        (const float4*)feat, (ushort4*)gb, n4,
        (const float4*)W, (ushort4*)wb, nw4,
        dst, bcnt, n_edges, nbkt);

    gcn_bscan<<<1, MAXBKT, 0, stream>>>(bcnt, bbase, nbkt);

    int pblocks = (n_edges + PLACE_CHUNK - 1) / PLACE_CHUNK;
    gcn_place<<<pblocks, 512, 0, stream>>>(src, dst, bbase, bcur, pairs,
                                           n_edges, nbkt);

    gcn_agg_mfma<<<nbkt, 512, 0, stream>>>(gb, wb, pairs, bbase, bias, out,
                                           n_nodes);
  } else {
    size_t agg_bytes = (size_t)n_nodes * DFEAT * sizeof(float);
    float* agg = (ws_size >= agg_bytes) ? (float*)d_ws : out;
    hipMemsetAsync(agg, 0, agg_bytes, stream);
    long long st = (long long)n_edges * 16;
    gcn_scatter_kernel<<<(int)((st + 255) / 256), 256, 0, stream>>>(
        (const float4*)feat, src, dst, agg, n_edges);
    int gblocks = (n_nodes + 15) / 16;
    gcn_gemm_kernel<<<gblocks, 256, 0, stream>>>(feat, agg, W, bias, out,
                                                 n_nodes);
  }
}

// Round 8
// 749.313 us; speedup vs baseline: 1.0147x; 1.0147x over previous
//
#include <hip/hip_runtime.h>

#define DFEAT 64
#define BKSZ 256            // nodes per bucket
#define SB 8                // log2(BKSZ)
#define MAXBKT 512          // scan width; requires nbkt <= 512
#define PLACE_CHUNK 8192

typedef __attribute__((ext_vector_type(8))) short bf16x8;
typedef __attribute__((ext_vector_type(4))) float f32x4;

__device__ inline unsigned short f2bf(float f) {
  unsigned int x = __float_as_uint(f);
  return (unsigned short)((x + 0x7fffu + ((x >> 16) & 1u)) >> 16);
}
__device__ inline float bf2f(unsigned short u) {
  return __uint_as_float(((unsigned int)u) << 16);
}

// Native LDS float atomic add.  Generic pointers to __shared__ carry the LDS
// byte offset in their low 32 bits (apertures are 4GB-aligned), which is
// exactly the VGPR address ds_add_f32 wants.  Fire-and-forget (no return,
// lgkmcnt-counted); caller must s_waitcnt lgkmcnt(0) before the barrier.
__device__ inline void lds_fadd(float* p, float v) {
  unsigned off = (unsigned)(unsigned long long)p;
  asm volatile("ds_add_f32 %0, %1" :: "v"(off), "v"(v));
}

// ===========================================================================
// K1: fp32->bf16 conversion (feat + sentinel zero row + W) AND bucket hist.
// ===========================================================================
__global__ __launch_bounds__(256) void gcn_prep(
    const float4* __restrict__ feat4, ushort4* __restrict__ gb4, int n4,
    const float4* __restrict__ w4, ushort4* __restrict__ wb4, int nw4,
    const int* __restrict__ dst, int* __restrict__ bcnt,
    int n_edges, int nbkt) {
  int total = n4 + 16 + nw4;
  for (int i = blockIdx.x * 256 + threadIdx.x; i < total; i += gridDim.x * 256) {
    if (i < n4) {
      float4 f = feat4[i];
      ushort4 u;
      u.x = f2bf(f.x); u.y = f2bf(f.y); u.z = f2bf(f.z); u.w = f2bf(f.w);
      gb4[i] = u;
    } else if (i < n4 + 16) {
      gb4[i] = (ushort4){0, 0, 0, 0};          // sentinel row (node n_nodes)
    } else {
      float4 f = w4[i - n4 - 16];
      ushort4 u;
      u.x = f2bf(f.x); u.y = f2bf(f.y); u.z = f2bf(f.z); u.w = f2bf(f.w);
      wb4[i - n4 - 16] = u;
    }
  }
  __shared__ int h[MAXBKT];
  for (int i = threadIdx.x; i < nbkt; i += 256) h[i] = 0;
  __syncthreads();
  int ne4 = n_edges >> 2;
  const int4* d4 = (const int4*)dst;
  for (int e = blockIdx.x * 256 + threadIdx.x; e < ne4; e += gridDim.x * 256) {
    int4 v = d4[e];
    atomicAdd(&h[v.x >> SB], 1);
    atomicAdd(&h[v.y >> SB], 1);
    atomicAdd(&h[v.z >> SB], 1);
    atomicAdd(&h[v.w >> SB], 1);
  }
  if (blockIdx.x == 0)
    for (int e = (ne4 << 2) + threadIdx.x; e < n_edges; e += 256)
      atomicAdd(&h[dst[e] >> SB], 1);
  __syncthreads();
  for (int i = threadIdx.x; i < nbkt; i += 256)
    if (h[i]) atomicAdd(&bcnt[i], h[i]);
}

// ===========================================================================
// K2: group edges by bucket as packed u32 (src | local<<24).  Bucket bases
// come from a LOCAL LDS scan of bcnt (no separate scan kernel); bcur holds
// relative cursors (pre-zeroed).
// ===========================================================================
__global__ __launch_bounds__(512) void gcn_place(
    const int* __restrict__ src, const int* __restrict__ dst,
    const int* __restrict__ bcnt, int* __restrict__ bcur,
    unsigned int* __restrict__ pairs, int n_edges, int nbkt) {
  __shared__ int sc[2][MAXBKT];
  __shared__ int cnt[MAXBKT];
  __shared__ int base[MAXBKT];
  int t = threadIdx.x;
  sc[0][t] = (t < nbkt) ? bcnt[t] : 0;
  __syncthreads();
  int pin = 0;
  for (int s = 1; s < MAXBKT; s <<= 1) {
    int po = pin ^ 1;
    int v = sc[pin][t];
    if (t >= s) v += sc[pin][t - s];
    sc[po][t] = v;
    __syncthreads();
    pin = po;
  }
  int bb = (t == 0) ? 0 : sc[pin][t - 1];   // exclusive bucket base

  cnt[t] = 0;
  __syncthreads();
  int e0 = blockIdx.x * PLACE_CHUNK;
  int e1 = min(e0 + PLACE_CHUNK, n_edges);
  for (int e = e0 + t; e < e1; e += 512) atomicAdd(&cnt[dst[e] >> SB], 1);
  __syncthreads();
  {
    int c = cnt[t];
    base[t] = bb + (c ? atomicAdd(&bcur[t], c) : 0);
    cnt[t] = 0;   // reuse as local cursor
  }
  __syncthreads();
  for (int e = e0 + t; e < e1; e += 512) {
    int d = dst[e];
    int b = d >> SB;
    int pos = base[b] + atomicAdd(&cnt[b], 1);
    pairs[pos] = (unsigned)src[e] | ((unsigned)(d & (BKSZ - 1)) << 24);
  }
}

// ===========================================================================
// K3: fused bucket-LDS aggregation + concat + MFMA Linear.
// One block (512 thr = 8 waves) per 256-node bucket.
//
// Accumulate: one edge per step; readlane broadcasts the packed id (VALU,
// uniform j), all 64 lanes load feat[s][lane] (2B, 128B coalesced, SGPR
// base) and ds_add_f32 into acc[loc][lane] (stride-1 across lanes -> 2
// lanes/bank = conflict-free; native atomic, no CAS).
//
// MFMA epilogue: per wave 2 tiles of 16 nodes.  A-frag feat half from the
// global bf16 table; agg half from LDS f32 + cvt.  W in registers as
// B-frags.  C/D: col=lane&15, row=(lane>>4)*4+reg.
// ===========================================================================
__global__ __launch_bounds__(512, 4) void gcn_agg_mfma(
    const unsigned short* __restrict__ gb,   // [N+1][64] bf16, row N zeros
    const unsigned short* __restrict__ wb,   // [64][128] bf16 W
    const unsigned int* __restrict__ pairs,
    const int* __restrict__ bcnt,
    const float* __restrict__ bias,
    float* __restrict__ out,
    int n_nodes, int nbkt) {
  __shared__ float acc[BKSZ][68];            // 69632 B
  __shared__ int sc[2][MAXBKT];              // +4 KB -> 2 blocks/CU
  int tid = threadIdx.x;
  int wave = tid >> 6, lane = tid & 63;
  int b = blockIdx.x;
  int n0 = b << SB;

  // local bucket scan -> [e0, e1)
  sc[0][tid] = (tid < nbkt) ? bcnt[tid] : 0;
  __syncthreads();
  int pin = 0;
  for (int s = 1; s < MAXBKT; s <<= 1) {
    int po = pin ^ 1;
    int v = sc[pin][tid];
    if (tid >= s) v += sc[pin][tid - s];
    sc[po][tid] = v;
    __syncthreads();
    pin = po;
  }
  int e0 = (b == 0) ? 0 : sc[pin][b - 1];
  int e1 = sc[pin][b];

  for (int i = tid; i < BKSZ * 68; i += 512) ((float*)acc)[i] = 0.f;
  __syncthreads();

  // ---- accumulate ----
  for (int base = e0 + wave * 64; base < e1; base += 512) {
    int rem = e1 - base;
    unsigned id = (lane < rem) ? pairs[base + lane] : 0u;
    int lim = min(64, rem);
#pragma unroll 4
    for (int j = 0; j < lim; ++j) {
      unsigned p = (unsigned)__builtin_amdgcn_readlane((int)id, j);
      int s = (int)(p & 0xFFFFFFu);
      int loc = (int)(p >> 24);
      float v = bf2f(gb[(size_t)s * DFEAT + (unsigned)lane]);
      lds_fadd(&acc[loc][lane], v);
    }
  }
  // drain this wave's asm-issued DS ops before the barrier (waitcnt pass
  // cannot see into inline asm).
  asm volatile("s_waitcnt lgkmcnt(0)");
  __syncthreads();

  // ---- MFMA epilogue ----
  int lrow = lane & 15, lkg = lane >> 4;
  bf16x8 wf[4][4];
#pragma unroll
  for (int kt = 0; kt < 4; ++kt)
#pragma unroll
    for (int jt = 0; jt < 4; ++jt)
      wf[kt][jt] =
          *(const bf16x8*)(wb + (jt * 16 + lrow) * 128 + kt * 32 + lkg * 8);

  float bj[4];
#pragma unroll
  for (int jt = 0; jt < 4; ++jt) bj[jt] = bias[jt * 16 + lrow];

#pragma unroll
  for (int ti = 0; ti < 2; ++ti) {
    int tile = wave * 2 + ti;
    int nrow = n0 + tile * 16 + lrow;
    int nload = (nrow < n_nodes) ? nrow : n_nodes;   // sentinel row if OOB

    f32x4 cacc[4];
#pragma unroll
    for (int jt = 0; jt < 4; ++jt) cacc[jt] = (f32x4){0.f, 0.f, 0.f, 0.f};

#pragma unroll
    for (int kt = 0; kt < 2; ++kt) {   // feat half from global bf16 table
      bf16x8 af = *(const bf16x8*)(gb + (size_t)nload * DFEAT + kt * 32 + lkg * 8);
#pragma unroll
      for (int jt = 0; jt < 4; ++jt)
        cacc[jt] = __builtin_amdgcn_mfma_f32_16x16x32_bf16(af, wf[kt][jt],
                                                           cacc[jt], 0, 0, 0);
    }
#pragma unroll
    for (int kt = 2; kt < 4; ++kt) {   // agg half from LDS f32
      const float* ap = &acc[tile * 16 + lrow][(kt - 2) * 32 + lkg * 8];
      float4 lo = *(const float4*)ap;
      float4 hi = *(const float4*)(ap + 4);
      bf16x8 af;
      af[0] = (short)f2bf(lo.x); af[1] = (short)f2bf(lo.y);
      af[2] = (short)f2bf(lo.z); af[3] = (short)f2bf(lo.w);
      af[4] = (short)f2bf(hi.x); af[5] = (short)f2bf(hi.y);
      af[6] = (short)f2bf(hi.z); af[7] = (short)f2bf(hi.w);
#pragma unroll
      for (int jt = 0; jt < 4; ++jt)
        cacc[jt] = __builtin_amdgcn_mfma_f32_16x16x32_bf16(af, wf[kt][jt],
                                                           cacc[jt], 0, 0, 0);
    }

#pragma unroll
    for (int jt = 0; jt < 4; ++jt) {
#pragma unroll
      for (int r = 0; r < 4; ++r) {
        int n = n0 + tile * 16 + lkg * 4 + r;
        if (n < n_nodes) out[n * DFEAT + jt * 16 + lrow] = cacc[jt][r] + bj[jt];
      }
    }
  }
}

// ===========================================================================
// Last-resort fallback: atomic scatter + separate vector GEMM.
// ===========================================================================
__global__ __launch_bounds__(256) void gcn_scatter_kernel(
    const float4* __restrict__ feat4, const int* __restrict__ src,
    const int* __restrict__ dst, float* __restrict__ agg, int n_edges) {
  long long gid = (long long)blockIdx.x * blockDim.x + threadIdx.x;
  int e = (int)(gid >> 4);
  int c = (int)(gid & 15);
  if (e >= n_edges) return;
  float4 v = feat4[src[e] * 16 + c];
  float* p = agg + dst[e] * DFEAT + c * 4;
  atomicAdd(p + 0, v.x);
  atomicAdd(p + 1, v.y);
  atomicAdd(p + 2, v.z);
  atomicAdd(p + 3, v.w);
}

__global__ __launch_bounds__(256) void gcn_gemm_kernel(
    const float* __restrict__ feat, const float* __restrict__ agg,
    const float* __restrict__ W, const float* __restrict__ bias,
    float* __restrict__ out, int n_nodes) {
  __shared__ float4 Wl4[2048];
  __shared__ __align__(16) float hlf[16][128];
  int tid = threadIdx.x;
  for (int i = tid; i < 2048; i += 256) {
    int j = i >> 5, k4 = i & 31;
    Wl4[k4 * 64 + (j ^ (k4 & 7))] = ((const float4*)W)[i];
  }
  int node0 = blockIdx.x * 16;
  int wave = tid >> 6, lane = tid & 63;
  int mbase = wave * 4;
#pragma unroll
  for (int r = 0; r < 4; ++r) {
    int n = node0 + mbase + r;
    if (n < n_nodes) {
      hlf[mbase + r][lane]      = feat[n * DFEAT + lane];
      hlf[mbase + r][64 + lane] = agg[n * DFEAT + lane];
    }
  }
  __syncthreads();
  float a0 = 0.f, a1 = 0.f, a2 = 0.f, a3 = 0.f;
#pragma unroll 4
  for (int k4 = 0; k4 < 32; ++k4) {
    float4 w  = Wl4[k4 * 64 + (lane ^ (k4 & 7))];
    float4 h0 = *((const float4*)&hlf[mbase + 0][k4 * 4]);
    float4 h1 = *((const float4*)&hlf[mbase + 1][k4 * 4]);
    float4 h2 = *((const float4*)&hlf[mbase + 2][k4 * 4]);
    float4 h3 = *((const float4*)&hlf[mbase + 3][k4 * 4]);
    a0 += w.x * h0.x + w.y * h0.y + w.z * h0.z + w.w * h0.w;
    a1 += w.x * h1.x + w.y * h1.y + w.z * h1.z + w.w * h1.w;
    a2 += w.x * h2.x + w.y * h2.y + w.z * h2.z + w.w * h2.w;
    a3 += w.x * h3.x + w.y * h3.y + w.z * h3.z + w.w * h3.w;
  }
  float bj = bias[lane];
  int n = node0 + mbase;
  if (n + 0 < n_nodes) out[(n + 0) * DFEAT + lane] = a0 + bj;
  if (n + 1 < n_nodes) out[(n + 1) * DFEAT + lane] = a1 + bj;
  if (n + 2 < n_nodes) out[(n + 2) * DFEAT + lane] = a2 + bj;
  if (n + 3 < n_nodes) out[(n + 3) * DFEAT + lane] = a3 + bj;
}

// ===========================================================================

extern "C" void kernel_launch(void* const* d_in, const int* in_sizes, int n_in,
                              void* d_out, int out_size, void* d_ws, size_t ws_size,
                              hipStream_t stream) {
  const float* feat = (const float*)d_in[0];
  const int*   src  = (const int*)d_in[1];
  const int*   dst  = (const int*)d_in[2];
  const float* W    = (const float*)d_in[3];
  const float* bias = (const float*)d_in[4];
  float* out = (float*)d_out;

  int n_nodes = in_sizes[0] / DFEAT;   // 100000
  int n_edges = in_sizes[1];           // 1600000
  int nbkt = (n_nodes + BKSZ - 1) >> SB;   // 391

  auto align_up = [](size_t x) { return (x + 255) & ~(size_t)255; };
  size_t pair_b = align_up((size_t)n_edges * 4);
  size_t bcnt_b = align_up((size_t)MAXBKT * 4);
  size_t bcur_b = align_up((size_t)MAXBKT * 4);
  size_t wb_b   = align_up((size_t)DFEAT * 128 * 2);
  size_t gb_b   = align_up((size_t)(n_nodes + 1) * DFEAT * 2);  // +sentinel
  size_t need   = pair_b + bcnt_b + bcur_b + wb_b + gb_b;

  bool ok = nbkt >= 1 && nbkt <= MAXBKT && ws_size >= need &&
            n_nodes < (1 << 24) - 1;

  if (ok) {
    char* p = (char*)d_ws;
    unsigned int* pairs = (unsigned int*)p;    p += pair_b;
    int* bcnt  = (int*)p;                      p += bcnt_b;
    int* bcur  = (int*)p;                      p += bcur_b;
    unsigned short* wb = (unsigned short*)p;   p += wb_b;
    unsigned short* gb = (unsigned short*)p;

    hipMemsetAsync(bcnt, 0, bcnt_b + bcur_b, stream);   // bcnt + bcur

    int n4 = n_nodes * (DFEAT / 4);
    int nw4 = DFEAT * 128 / 4;
    gcn_prep<<<1024, 256, 0, stream>>>(
        (const float4*)feat, (ushort4*)gb, n4,
        (const float4*)W, (ushort4*)wb, nw4,
        dst, bcnt, n_edges, nbkt);

    int pblocks = (n_edges + PLACE_CHUNK - 1) / PLACE_CHUNK;
    gcn_place<<<pblocks, 512, 0, stream>>>(src, dst, bcnt, bcur, pairs,
                                           n_edges, nbkt);

    gcn_agg_mfma<<<nbkt, 512, 0, stream>>>(gb, wb, pairs, bcnt, bias, out,
                                           n_nodes, nbkt);
  } else {
    size_t agg_bytes = (size_t)n_nodes * DFEAT * sizeof(float);
    float* agg = (ws_size >= agg_bytes) ? (float*)d_ws : out;
    hipMemsetAsync(agg, 0, agg_bytes, stream);
    long long st = (long long)n_edges * 16;
    gcn_scatter_kernel<<<(int)((st + 255) / 256), 256, 0, stream>>>(
        (const float4*)feat, src, dst, agg, n_edges);
    int gblocks = (n_nodes + 15) / 16;
    gcn_gemm_kernel<<<gblocks, 256, 0, stream>>>(feat, agg, W, bias, out,
                                                 n_nodes);
  }
}

// Round 9
// 122.978 us; speedup vs baseline: 6.1829x; 6.0931x over previous
//
#include <hip/hip_runtime.h>

#define DFEAT 64
#define BKSZ 512            // nodes per bucket (CSR build)
#define SB 9                // log2(BKSZ)
#define NBKT_PAD 256        // max buckets (scan width); nbkt <= 256
#define PLACE_CHUNK 8192
#define FILL_CAP 12288      // LDS pair cache per bucket (48KB)

typedef __attribute__((ext_vector_type(8))) short bf16x8;
typedef __attribute__((ext_vector_type(4))) float f32x4;

__device__ inline unsigned short f2bf(float f) {
  unsigned int x = __float_as_uint(f);
  return (unsigned short)((x + 0x7fffu + ((x >> 16) & 1u)) >> 16);
}

// ===========================================================================
// K1: fp32->bf16 conversion (feat + sentinel zero row + W) AND bucket hist.
// ===========================================================================
__global__ __launch_bounds__(256) void gcn_prep(
    const float4* __restrict__ feat4, ushort4* __restrict__ gb4, int n4,
    const float4* __restrict__ w4, ushort4* __restrict__ wb4, int nw4,
    const int* __restrict__ dst, int* __restrict__ bcnt,
    int n_edges, int nbkt) {
  int total = n4 + 16 + nw4;
  for (int i = blockIdx.x * 256 + threadIdx.x; i < total; i += gridDim.x * 256) {
    if (i < n4) {
      float4 f = feat4[i];
      ushort4 u;
      u.x = f2bf(f.x); u.y = f2bf(f.y); u.z = f2bf(f.z); u.w = f2bf(f.w);
      gb4[i] = u;
    } else if (i < n4 + 16) {
      gb4[i] = (ushort4){0, 0, 0, 0};          // sentinel row (node n_nodes)
    } else {
      float4 f = w4[i - n4 - 16];
      ushort4 u;
      u.x = f2bf(f.x); u.y = f2bf(f.y); u.z = f2bf(f.z); u.w = f2bf(f.w);
      wb4[i - n4 - 16] = u;
    }
  }
  __shared__ int h[NBKT_PAD];
  for (int i = threadIdx.x; i < nbkt; i += 256) h[i] = 0;
  __syncthreads();
  int ne4 = n_edges >> 2;
  const int4* d4 = (const int4*)dst;
  for (int e = blockIdx.x * 256 + threadIdx.x; e < ne4; e += gridDim.x * 256) {
    int4 v = d4[e];
    atomicAdd(&h[v.x >> SB], 1);
    atomicAdd(&h[v.y >> SB], 1);
    atomicAdd(&h[v.z >> SB], 1);
    atomicAdd(&h[v.w >> SB], 1);
  }
  if (blockIdx.x == 0)
    for (int e = (ne4 << 2) + threadIdx.x; e < n_edges; e += 256)
      atomicAdd(&h[dst[e] >> SB], 1);
  __syncthreads();
  for (int i = threadIdx.x; i < nbkt; i += 256)
    if (h[i]) atomicAdd(&bcnt[i], h[i]);
}

// ===========================================================================
// K2: place edges as packed u32 (src | local<<23), grouped by bucket.
// Single global pass: src/dst read once; packed value + bucket id cached in
// LDS, placement writes from LDS.  Bucket bases from a LOCAL scan of bcnt;
// bcur holds relative cursors (pre-zeroed).
// ===========================================================================
__global__ __launch_bounds__(512) void gcn_place(
    const int* __restrict__ src, const int* __restrict__ dst,
    const int* __restrict__ bcnt, int* __restrict__ bcur,
    unsigned int* __restrict__ pairs, int n_edges, int nbkt) {
  __shared__ int sc[2][NBKT_PAD];                  // 2 KB
  __shared__ int cnt[NBKT_PAD];                    // 1 KB
  __shared__ int base[NBKT_PAD];                   // 1 KB
  __shared__ unsigned int pk[PLACE_CHUNK];         // 32 KB
  __shared__ unsigned char bk[PLACE_CHUNK];        // 8 KB
  int t = threadIdx.x;

  if (t < NBKT_PAD) sc[0][t] = (t < nbkt) ? bcnt[t] : 0;
  __syncthreads();
  int pin = 0;
  for (int s = 1; s < NBKT_PAD; s <<= 1) {
    int po = pin ^ 1;
    if (t < NBKT_PAD) {
      int v = sc[pin][t];
      if (t >= s) v += sc[pin][t - s];
      sc[po][t] = v;
    }
    __syncthreads();
    pin = po;
  }
  int bb = 0;
  if (t < NBKT_PAD) bb = (t == 0) ? 0 : sc[pin][t - 1];
  if (t < NBKT_PAD) cnt[t] = 0;
  __syncthreads();

  int e0 = blockIdx.x * PLACE_CHUNK;
  int e1 = min(e0 + PLACE_CHUNK, n_edges);
  for (int e = e0 + t; e < e1; e += 512) {
    int d = dst[e];
    int s = src[e];
    int b = d >> SB;
    pk[e - e0] = (unsigned)s | ((unsigned)(d & (BKSZ - 1)) << 23);
    bk[e - e0] = (unsigned char)b;
    atomicAdd(&cnt[b], 1);
  }
  __syncthreads();
  if (t < NBKT_PAD) {
    int c = cnt[t];
    base[t] = bb + (c ? atomicAdd(&bcur[t], c) : 0);
    cnt[t] = 0;   // reuse as local cursor
  }
  __syncthreads();
  for (int e = e0 + t; e < e1; e += 512) {
    int b = bk[e - e0];
    int pos = base[b] + atomicAdd(&cnt[b], 1);
    pairs[pos] = pk[e - e0];
  }
}

// ===========================================================================
// K3: per-bucket fill.  Bucket range from local scan of bcnt; bucket's
// packed pairs cached in LDS (single global read) when they fit (FILL_CAP);
// node-degree hist -> scan -> offsets + cursor placement of edge_src.
// ===========================================================================
__global__ __launch_bounds__(512) void gcn_fillk(
    const unsigned int* __restrict__ pairs, const int* __restrict__ bcnt,
    int* __restrict__ offsets, int* __restrict__ edge_src,
    int n_nodes, int n_edges, int nbkt) {
  __shared__ int sc[2][NBKT_PAD];       // 2 KB
  __shared__ int deg[BKSZ];             // 2 KB
  __shared__ int buf[2][BKSZ];          // 4 KB
  __shared__ int cur[BKSZ];             // 2 KB
  __shared__ unsigned int lp[FILL_CAP]; // 48 KB  -> ~2 blocks/CU
  int b = blockIdx.x, t = threadIdx.x;

  if (t < NBKT_PAD) sc[0][t] = (t < nbkt) ? bcnt[t] : 0;
  __syncthreads();
  int pin = 0;
  for (int s = 1; s < NBKT_PAD; s <<= 1) {
    int po = pin ^ 1;
    if (t < NBKT_PAD) {
      int v = sc[pin][t];
      if (t >= s) v += sc[pin][t - s];
      sc[po][t] = v;
    }
    __syncthreads();
    pin = po;
  }
  int e0 = (b == 0) ? 0 : sc[pin][b - 1];
  int e1 = sc[pin][b];
  int ne = e1 - e0;
  int n0 = b << SB;
  bool fits = (ne <= FILL_CAP);

  deg[t] = 0;
  __syncthreads();
  if (fits) {
    for (int i = t; i < ne; i += 512) {
      unsigned p = pairs[e0 + i];
      lp[i] = p;
      atomicAdd(&deg[p >> 23], 1);
    }
  } else {
    for (int i = t; i < ne; i += 512) atomicAdd(&deg[pairs[e0 + i] >> 23], 1);
  }
  __syncthreads();
  buf[0][t] = deg[t];
  __syncthreads();
  pin = 0;
  for (int s = 1; s < BKSZ; s <<= 1) {
    int po = pin ^ 1;
    int v = buf[pin][t];
    if (t >= s) v += buf[pin][t - s];
    buf[po][t] = v;
    __syncthreads();
    pin = po;
  }
  int excl = (t == 0) ? 0 : buf[pin][t - 1];
  cur[t] = excl;
  int n = n0 + t;
  if (n < n_nodes) offsets[n] = e0 + excl;
  if (b == nbkt - 1 && t == 0) offsets[n_nodes] = n_edges;
  __syncthreads();
  if (fits) {
    for (int i = t; i < ne; i += 512) {
      unsigned p = lp[i];
      int pos = atomicAdd(&cur[p >> 23], 1);
      edge_src[e0 + pos] = (int)(p & 0x7FFFFFu);
    }
  } else {
    for (int i = t; i < ne; i += 512) {
      unsigned p = pairs[e0 + i];
      int pos = atomicAdd(&cur[p >> 23], 1);
      edge_src[e0 + pos] = (int)(p & 0x7FFFFFu);
    }
  }
}

// ===========================================================================
// K4: fused gather + concat + MFMA Linear (r6 verbatim — measured 57us).
// Block = 4 waves; each wave owns 16 nodes, fully independent (no barriers).
// Gather: 4 edges per load instruction (lane = 16-lane group q per edge,
// ushort4 = 8B/lane, 512B/wave-inst); sentinel id = n_nodes (zero row) pads
// every batch -> no serial tails.  h staged bf16 in wave-private LDS,
// XOR-swizzled; W in registers as B-frags; C/D: col=lane&15,
// row=(lane>>4)*4+reg.
// ===========================================================================
__global__ __launch_bounds__(256, 4) void gcn_gather_mfma(
    const ushort4* __restrict__ gb4,         // [N+1][16] bf16, row N = zeros
    const unsigned short* __restrict__ wb,   // [64][128] bf16 W
    const int* __restrict__ edge_src,
    const int* __restrict__ offsets,
    const float* __restrict__ bias,          // [64]
    float* __restrict__ out,                 // [N][64]
    int n_nodes) {
  __shared__ unsigned short hl[4][16 * 128];   // 16 KB total
  int tid = threadIdx.x;
  int wave = tid >> 6, lane = tid & 63;
  int q = lane >> 4, kk = lane & 15;
  int lrow = lane & 15, lkg = lane >> 4;
  unsigned short* myhl = hl[wave];
  int node0 = blockIdx.x * 64 + wave * 16;
  const int SENT = n_nodes;

  for (int r = 0; r < 16; ++r) {
    int n = node0 + r;
    if (n >= n_nodes) break;
    int off = offsets[n];
    int deg = offsets[n + 1] - off;

    float4 a0 = {0.f, 0.f, 0.f, 0.f}, a1 = a0, a2 = a0, a3 = a0;
    for (int base = 0; base < deg; base += 64) {
      int lim = min(64, deg - base);
      int id = (base + lane < deg) ? edge_src[off + base + lane] : SENT;
      for (int j = 0; j < lim; j += 16) {
        int s0 = __shfl(id, j + q);
        int s1 = __shfl(id, j + 4 + q);
        int s2 = __shfl(id, j + 8 + q);
        int s3 = __shfl(id, j + 12 + q);
        uint2 w0 = *(const uint2*)&gb4[s0 * 16 + kk];
        uint2 w1 = *(const uint2*)&gb4[s1 * 16 + kk];
        uint2 w2 = *(const uint2*)&gb4[s2 * 16 + kk];
        uint2 w3 = *(const uint2*)&gb4[s3 * 16 + kk];
        a0.x += __uint_as_float(w0.x << 16);
        a0.y += __uint_as_float(w0.x & 0xffff0000u);
        a0.z += __uint_as_float(w0.y << 16);
        a0.w += __uint_as_float(w0.y & 0xffff0000u);
        a1.x += __uint_as_float(w1.x << 16);
        a1.y += __uint_as_float(w1.x & 0xffff0000u);
        a1.z += __uint_as_float(w1.y << 16);
        a1.w += __uint_as_float(w1.y & 0xffff0000u);
        a2.x += __uint_as_float(w2.x << 16);
        a2.y += __uint_as_float(w2.x & 0xffff0000u);
        a2.z += __uint_as_float(w2.y << 16);
        a2.w += __uint_as_float(w2.y & 0xffff0000u);
        a3.x += __uint_as_float(w3.x << 16);
        a3.y += __uint_as_float(w3.x & 0xffff0000u);
        a3.z += __uint_as_float(w3.y << 16);
        a3.w += __uint_as_float(w3.y & 0xffff0000u);
      }
    }
    float4 acc;
    acc.x = (a0.x + a1.x) + (a2.x + a3.x);
    acc.y = (a0.y + a1.y) + (a2.y + a3.y);
    acc.z = (a0.z + a1.z) + (a2.z + a3.z);
    acc.w = (a0.w + a1.w) + (a2.w + a3.w);
    acc.x += __shfl_xor(acc.x, 16); acc.x += __shfl_xor(acc.x, 32);
    acc.y += __shfl_xor(acc.y, 16); acc.y += __shfl_xor(acc.y, 32);
    acc.z += __shfl_xor(acc.z, 16); acc.z += __shfl_xor(acc.z, 32);
    acc.w += __shfl_xor(acc.w, 16); acc.w += __shfl_xor(acc.w, 32);

    unsigned swz = (unsigned)((r & 7) << 4);
    char* rowp = (char*)(myhl + r * 128);
    if (q == 0) {                 // agg half: bytes [128,256)
      ushort4 pk;
      pk.x = f2bf(acc.x); pk.y = f2bf(acc.y);
      pk.z = f2bf(acc.z); pk.w = f2bf(acc.w);
      *(ushort4*)(rowp + ((128u + 8u * (unsigned)kk) ^ swz)) = pk;
    } else if (q == 1) {          // feat half: bytes [0,128)
      ushort4 f = gb4[n * 16 + kk];
      *(ushort4*)(rowp + ((8u * (unsigned)kk) ^ swz)) = f;
    }
  }

  bf16x8 wf[4][4];
#pragma unroll
  for (int kt = 0; kt < 4; ++kt)
#pragma unroll
    for (int jt = 0; jt < 4; ++jt)
      wf[kt][jt] =
          *(const bf16x8*)(wb + (jt * 16 + lrow) * 128 + kt * 32 + lkg * 8);

  f32x4 acc[4];
#pragma unroll
  for (int jt = 0; jt < 4; ++jt) acc[jt] = (f32x4){0.f, 0.f, 0.f, 0.f};

  unsigned aswz = (unsigned)((lrow & 7) << 4);
  const char* arow = (const char*)(myhl + lrow * 128);
#pragma unroll
  for (int kt = 0; kt < 4; ++kt) {
    bf16x8 af = *(const bf16x8*)(arow + ((unsigned)(kt * 64 + lkg * 16) ^ aswz));
#pragma unroll
    for (int jt = 0; jt < 4; ++jt)
      acc[jt] = __builtin_amdgcn_mfma_f32_16x16x32_bf16(af, wf[kt][jt],
                                                        acc[jt], 0, 0, 0);
  }

#pragma unroll
  for (int jt = 0; jt < 4; ++jt) {
    float bj = bias[jt * 16 + lrow];
#pragma unroll
    for (int r = 0; r < 4; ++r) {
      int n = node0 + lkg * 4 + r;
      if (n < n_nodes) out[n * DFEAT + jt * 16 + lrow] = acc[jt][r] + bj;
    }
  }
}

// ===========================================================================
// Last-resort fallback: atomic scatter + separate vector GEMM.
// ===========================================================================
__global__ __launch_bounds__(256) void gcn_scatter_kernel(
    const float4* __restrict__ feat4, const int* __restrict__ src,
    const int* __restrict__ dst, float* __restrict__ agg, int n_edges) {
  long long gid = (long long)blockIdx.x * blockDim.x + threadIdx.x;
  int e = (int)(gid >> 4);
  int c = (int)(gid & 15);
  if (e >= n_edges) return;
  float4 v = feat4[src[e] * 16 + c];
  float* p = agg + dst[e] * DFEAT + c * 4;
  atomicAdd(p + 0, v.x);
  atomicAdd(p + 1, v.y);
  atomicAdd(p + 2, v.z);
  atomicAdd(p + 3, v.w);
}

__global__ __launch_bounds__(256) void gcn_gemm_kernel(
    const float* __restrict__ feat, const float* __restrict__ agg,
    const float* __restrict__ W, const float* __restrict__ bias,
    float* __restrict__ out, int n_nodes) {
  __shared__ float4 Wl4[2048];
  __shared__ __align__(16) float hlf[16][128];
  int tid = threadIdx.x;
  for (int i = tid; i < 2048; i += 256) {
    int j = i >> 5, k4 = i & 31;
    Wl4[k4 * 64 + (j ^ (k4 & 7))] = ((const float4*)W)[i];
  }
  int node0 = blockIdx.x * 16;
  int wave = tid >> 6, lane = tid & 63;
  int mbase = wave * 4;
#pragma unroll
  for (int r = 0; r < 4; ++r) {
    int n = node0 + mbase + r;
    if (n < n_nodes) {
      hlf[mbase + r][lane]      = feat[n * DFEAT + lane];
      hlf[mbase + r][64 + lane] = agg[n * DFEAT + lane];
    }
  }
  __syncthreads();
  float a0 = 0.f, a1 = 0.f, a2 = 0.f, a3 = 0.f;
#pragma unroll 4
  for (int k4 = 0; k4 < 32; ++k4) {
    float4 w  = Wl4[k4 * 64 + (lane ^ (k4 & 7))];
    float4 h0 = *((const float4*)&hlf[mbase + 0][k4 * 4]);
    float4 h1 = *((const float4*)&hlf[mbase + 1][k4 * 4]);
    float4 h2 = *((const float4*)&hlf[mbase + 2][k4 * 4]);
    float4 h3 = *((const float4*)&hlf[mbase + 3][k4 * 4]);
    a0 += w.x * h0.x + w.y * h0.y + w.z * h0.z + w.w * h0.w;
    a1 += w.x * h1.x + w.y * h1.y + w.z * h1.z + w.w * h1.w;
    a2 += w.x * h2.x + w.y * h2.y + w.z * h2.z + w.w * h2.w;
    a3 += w.x * h3.x + w.y * h3.y + w.z * h3.z + w.w * h3.w;
  }
  float bj = bias[lane];
  int n = node0 + mbase;
  if (n + 0 < n_nodes) out[(n + 0) * DFEAT + lane] = a0 + bj;
  if (n + 1 < n_nodes) out[(n + 1) * DFEAT + lane] = a1 + bj;
  if (n + 2 < n_nodes) out[(n + 2) * DFEAT + lane] = a2 + bj;
  if (n + 3 < n_nodes) out[(n + 3) * DFEAT + lane] = a3 + bj;
}

// ===========================================================================

extern "C" void kernel_launch(void* const* d_in, const int* in_sizes, int n_in,
                              void* d_out, int out_size, void* d_ws, size_t ws_size,
                              hipStream_t stream) {
  const float* feat = (const float*)d_in[0];
  const int*   src  = (const int*)d_in[1];
  const int*   dst  = (const int*)d_in[2];
  const float* W    = (const float*)d_in[3];
  const float* bias = (const float*)d_in[4];
  float* out = (float*)d_out;

  int n_nodes = in_sizes[0] / DFEAT;   // 100000
  int n_edges = in_sizes[1];           // 1600000
  int nbkt = (n_nodes + BKSZ - 1) >> SB;   // 196

  auto align_up = [](size_t x) { return (x + 255) & ~(size_t)255; };
  size_t esrc_b = align_up((size_t)n_edges * 4);
  size_t off_b  = align_up((size_t)(n_nodes + 1) * 4);
  size_t bcnt_b = align_up((size_t)NBKT_PAD * 4);
  size_t bcur_b = align_up((size_t)NBKT_PAD * 4);
  size_t wb_b   = align_up((size_t)DFEAT * 128 * 2);
  size_t gb_b   = align_up((size_t)(n_nodes + 1) * DFEAT * 2);  // +sentinel
  size_t need   = esrc_b + off_b + bcnt_b + bcur_b + wb_b + gb_b;

  bool pairs_fit = (size_t)out_size * 4 >= (size_t)n_edges * 4;
  bool ok = pairs_fit && nbkt >= 1 && nbkt <= NBKT_PAD && ws_size >= need &&
            n_nodes < (1 << 23);

  if (ok) {
    char* p = (char*)d_ws;
    int* edge_src = (int*)p;   p += esrc_b;
    int* offsets  = (int*)p;   p += off_b;
    int* bcnt     = (int*)p;   p += bcnt_b;
    int* bcur     = (int*)p;   p += bcur_b;
    unsigned short* wb = (unsigned short*)p;   p += wb_b;
    unsigned short* gb = (unsigned short*)p;
    unsigned int* pairs = (unsigned int*)d_out;  // dead before out is written

    hipMemsetAsync(bcnt, 0, bcnt_b + bcur_b, stream);   // bcnt + bcur

    int n4 = n_nodes * (DFEAT / 4);
    int nw4 = DFEAT * 128 / 4;
    gcn_prep<<<1024, 256, 0, stream>>>(
        (const float4*)feat, (ushort4*)gb, n4,
        (const float4*)W, (ushort4*)wb, nw4,
        dst, bcnt, n_edges, nbkt);

    int pblocks = (n_edges + PLACE_CHUNK - 1) / PLACE_CHUNK;
    gcn_place<<<pblocks, 512, 0, stream>>>(src, dst, bcnt, bcur, pairs,
                                           n_edges, nbkt);

    gcn_fillk<<<nbkt, 512, 0, stream>>>(pairs, bcnt, offsets, edge_src,
                                        n_nodes, n_edges, nbkt);

    int gblocks = (n_nodes + 63) / 64;
    gcn_gather_mfma<<<gblocks, 256, 0, stream>>>(
        (const ushort4*)gb, wb, edge_src, offsets, bias, out, n_nodes);
  } else {
    size_t agg_bytes = (size_t)n_nodes * DFEAT * sizeof(float);
    float* agg = (ws_size >= agg_bytes) ? (float*)d_ws : out;
    hipMemsetAsync(agg, 0, agg_bytes, stream);
    long long st = (long long)n_edges * 16;
    gcn_scatter_kernel<<<(int)((st + 255) / 256), 256, 0, stream>>>(
        (const float4*)feat, src, dst, agg, n_edges);
    int gblocks = (n_nodes + 15) / 16;
    gcn_gemm_kernel<<<gblocks, 256, 0, stream>>>(feat, agg, W, bias, out,
                                                 n_nodes);
  }
}

// Round 10
// 119.480 us; speedup vs baseline: 6.3640x; 1.0293x over previous
//
#include <hip/hip_runtime.h>

#define DFEAT 64
#define BKSZ 512            // nodes per bucket (CSR build)
#define SB 9                // log2(BKSZ)
#define NBKT_PAD 256        // max buckets (scan width); nbkt <= 256
#define PLACE_CHUNK 4096
#define FILL_CAP 12288      // LDS pair cache per bucket (48KB)

typedef __attribute__((ext_vector_type(8))) short bf16x8;
typedef __attribute__((ext_vector_type(4))) float f32x4;

__device__ inline unsigned short f2bf(float f) {
  unsigned int x = __float_as_uint(f);
  return (unsigned short)((x + 0x7fffu + ((x >> 16) & 1u)) >> 16);
}

// ===========================================================================
// K1: fp32->bf16 conversion (feat + sentinel zero row + W) AND bucket hist.
// ===========================================================================
__global__ __launch_bounds__(256) void gcn_prep(
    const float4* __restrict__ feat4, ushort4* __restrict__ gb4, int n4,
    const float4* __restrict__ w4, ushort4* __restrict__ wb4, int nw4,
    const int* __restrict__ dst, int* __restrict__ bcnt,
    int n_edges, int nbkt) {
  int total = n4 + 16 + nw4;
  for (int i = blockIdx.x * 256 + threadIdx.x; i < total; i += gridDim.x * 256) {
    if (i < n4) {
      float4 f = feat4[i];
      ushort4 u;
      u.x = f2bf(f.x); u.y = f2bf(f.y); u.z = f2bf(f.z); u.w = f2bf(f.w);
      gb4[i] = u;
    } else if (i < n4 + 16) {
      gb4[i] = (ushort4){0, 0, 0, 0};          // sentinel row (node n_nodes)
    } else {
      float4 f = w4[i - n4 - 16];
      ushort4 u;
      u.x = f2bf(f.x); u.y = f2bf(f.y); u.z = f2bf(f.z); u.w = f2bf(f.w);
      wb4[i - n4 - 16] = u;
    }
  }
  __shared__ int h[NBKT_PAD];
  for (int i = threadIdx.x; i < nbkt; i += 256) h[i] = 0;
  __syncthreads();
  int ne4 = n_edges >> 2;
  const int4* d4 = (const int4*)dst;
  for (int e = blockIdx.x * 256 + threadIdx.x; e < ne4; e += gridDim.x * 256) {
    int4 v = d4[e];
    atomicAdd(&h[v.x >> SB], 1);
    atomicAdd(&h[v.y >> SB], 1);
    atomicAdd(&h[v.z >> SB], 1);
    atomicAdd(&h[v.w >> SB], 1);
  }
  if (blockIdx.x == 0)
    for (int e = (ne4 << 2) + threadIdx.x; e < n_edges; e += 256)
      atomicAdd(&h[dst[e] >> SB], 1);
  __syncthreads();
  for (int i = threadIdx.x; i < nbkt; i += 256)
    if (h[i]) atomicAdd(&bcnt[i], h[i]);
}

// ===========================================================================
// K2: place edges as packed u32 (src | local<<23), grouped by bucket.
// Single global pass; packed value + bucket id cached in LDS.  Bucket bases
// from a LOCAL scan of bcnt; bcur holds relative cursors (pre-zeroed).
// ===========================================================================
__global__ __launch_bounds__(512) void gcn_place(
    const int* __restrict__ src, const int* __restrict__ dst,
    const int* __restrict__ bcnt, int* __restrict__ bcur,
    unsigned int* __restrict__ pairs, int n_edges, int nbkt) {
  __shared__ int sc[2][NBKT_PAD];                  // 2 KB
  __shared__ int cnt[NBKT_PAD];                    // 1 KB
  __shared__ int base[NBKT_PAD];                   // 1 KB
  __shared__ unsigned int pk[PLACE_CHUNK];         // 16 KB
  __shared__ unsigned char bk[PLACE_CHUNK];        // 4 KB
  int t = threadIdx.x;

  if (t < NBKT_PAD) sc[0][t] = (t < nbkt) ? bcnt[t] : 0;
  __syncthreads();
  int pin = 0;
  for (int s = 1; s < NBKT_PAD; s <<= 1) {
    int po = pin ^ 1;
    if (t < NBKT_PAD) {
      int v = sc[pin][t];
      if (t >= s) v += sc[pin][t - s];
      sc[po][t] = v;
    }
    __syncthreads();
    pin = po;
  }
  int bb = 0;
  if (t < NBKT_PAD) bb = (t == 0) ? 0 : sc[pin][t - 1];
  if (t < NBKT_PAD) cnt[t] = 0;
  __syncthreads();

  int e0 = blockIdx.x * PLACE_CHUNK;
  int e1 = min(e0 + PLACE_CHUNK, n_edges);
  for (int e = e0 + t; e < e1; e += 512) {
    int d = dst[e];
    int s = src[e];
    int b = d >> SB;
    pk[e - e0] = (unsigned)s | ((unsigned)(d & (BKSZ - 1)) << 23);
    bk[e - e0] = (unsigned char)b;
    atomicAdd(&cnt[b], 1);
  }
  __syncthreads();
  if (t < NBKT_PAD) {
    int c = cnt[t];
    base[t] = bb + (c ? atomicAdd(&bcur[t], c) : 0);
    cnt[t] = 0;   // reuse as local cursor
  }
  __syncthreads();
  for (int e = e0 + t; e < e1; e += 512) {
    int b = bk[e - e0];
    int pos = base[b] + atomicAdd(&cnt[b], 1);
    pairs[pos] = pk[e - e0];
  }
}

// ===========================================================================
// K3: per-bucket fill.  Bucket range from local scan of bcnt; bucket's
// packed pairs cached in LDS when they fit; node-degree hist -> scan ->
// offsets + cursor placement of edge_src.
// ===========================================================================
__global__ __launch_bounds__(512) void gcn_fillk(
    const unsigned int* __restrict__ pairs, const int* __restrict__ bcnt,
    int* __restrict__ offsets, int* __restrict__ edge_src,
    int n_nodes, int n_edges, int nbkt) {
  __shared__ int sc[2][NBKT_PAD];       // 2 KB
  __shared__ int deg[BKSZ];             // 2 KB
  __shared__ int buf[2][BKSZ];          // 4 KB
  __shared__ int cur[BKSZ];             // 2 KB
  __shared__ unsigned int lp[FILL_CAP]; // 48 KB
  int b = blockIdx.x, t = threadIdx.x;

  if (t < NBKT_PAD) sc[0][t] = (t < nbkt) ? bcnt[t] : 0;
  __syncthreads();
  int pin = 0;
  for (int s = 1; s < NBKT_PAD; s <<= 1) {
    int po = pin ^ 1;
    if (t < NBKT_PAD) {
      int v = sc[pin][t];
      if (t >= s) v += sc[pin][t - s];
      sc[po][t] = v;
    }
    __syncthreads();
    pin = po;
  }
  int e0 = (b == 0) ? 0 : sc[pin][b - 1];
  int e1 = sc[pin][b];
  int ne = e1 - e0;
  int n0 = b << SB;
  bool fits = (ne <= FILL_CAP);

  deg[t] = 0;
  __syncthreads();
  if (fits) {
    for (int i = t; i < ne; i += 512) {
      unsigned p = pairs[e0 + i];
      lp[i] = p;
      atomicAdd(&deg[p >> 23], 1);
    }
  } else {
    for (int i = t; i < ne; i += 512) atomicAdd(&deg[pairs[e0 + i] >> 23], 1);
  }
  __syncthreads();
  buf[0][t] = deg[t];
  __syncthreads();
  pin = 0;
  for (int s = 1; s < BKSZ; s <<= 1) {
    int po = pin ^ 1;
    int v = buf[pin][t];
    if (t >= s) v += buf[pin][t - s];
    buf[po][t] = v;
    __syncthreads();
    pin = po;
  }
  int excl = (t == 0) ? 0 : buf[pin][t - 1];
  cur[t] = excl;
  int n = n0 + t;
  if (n < n_nodes) offsets[n] = e0 + excl;
  if (b == nbkt - 1 && t == 0) offsets[n_nodes] = n_edges;
  __syncthreads();
  if (fits) {
    for (int i = t; i < ne; i += 512) {
      unsigned p = lp[i];
      int pos = atomicAdd(&cur[p >> 23], 1);
      edge_src[e0 + pos] = (int)(p & 0x7FFFFFu);
    }
  } else {
    for (int i = t; i < ne; i += 512) {
      unsigned p = pairs[e0 + i];
      int pos = atomicAdd(&cur[p >> 23], 1);
      edge_src[e0 + pos] = (int)(p & 0x7FFFFFu);
    }
  }
}

// ===========================================================================
// K4: fused gather + concat + MFMA Linear.
// Block = 4 waves; each wave owns 16 nodes, fully independent (no barriers).
//
// Latency pipeline (new): (a) ONE vector load fetches offsets[node0..+16]
// per wave, per-node off/deg via __shfl; (b) node r+1's edge_src batch is
// prefetched while node r's gathers run -> ~1 exposed latency per node
// (was 3).  Gather: 4 edges per load inst (16-lane group q per edge,
// uint2 = 8B/lane); sentinel id = n_nodes (zero row) pads batches.
//
// LDS holds ONLY the agg half (16 rows x 64 bf16, XOR-swizzled); the feat
// A-frag is read directly from the global bf16 table in the epilogue
// (r7-proven).  W in registers as B-frags; A/B share the (lane>>4,elem)->k
// map so the k permutation cancels; C/D: col=lane&15, row=(lane>>4)*4+reg.
// ===========================================================================
__global__ __launch_bounds__(256, 4) void gcn_gather_mfma(
    const ushort4* __restrict__ gb4,         // [N+1][16] bf16, row N = zeros
    const unsigned short* __restrict__ wb,   // [64][128] bf16 W
    const int* __restrict__ edge_src,
    const int* __restrict__ offsets,
    const float* __restrict__ bias,          // [64]
    float* __restrict__ out,                 // [N][64]
    int n_nodes) {
  __shared__ unsigned short hl[4][16 * 64];   // 8 KB total (agg half only)
  int tid = threadIdx.x;
  int wave = tid >> 6, lane = tid & 63;
  int q = lane >> 4, kk = lane & 15;
  int lrow = lane & 15, lkg = lane >> 4;
  unsigned short* myhl = hl[wave];
  int node0 = blockIdx.x * 64 + wave * 16;
  const int SENT = n_nodes;

  // ---- one-shot offsets batch for this wave's 16 nodes ----
  int oidx = node0 + ((lane < 16) ? lane : 16);
  if (oidx > n_nodes) oidx = n_nodes;
  int offv = offsets[oidx];
  int nvalid = n_nodes - node0;
  if (nvalid > 16) nvalid = 16;

  // ---- prefetch node 0's first id batch ----
  int idv = SENT;
  if (nvalid > 0) {
    int o0 = __shfl(offv, 0);
    int d0 = __shfl(offv, 1) - o0;
    if (lane < d0) idv = edge_src[o0 + lane];
  }

  for (int r = 0; r < nvalid; ++r) {
    int off = __shfl(offv, r);
    int deg = __shfl(offv, r + 1) - off;

    // prefetch node r+1's first id batch (overlaps with this node's gathers)
    int idnx = SENT;
    if (r + 1 < nvalid) {
      int o2 = __shfl(offv, r + 1);
      int d2 = __shfl(offv, r + 2) - o2;
      if (lane < d2) idnx = edge_src[o2 + lane];
    }

    float4 a0 = {0.f, 0.f, 0.f, 0.f}, a1 = a0, a2 = a0, a3 = a0;
    auto proc16 = [&](int idreg, int j) {
      int s0 = __shfl(idreg, j + q);
      int s1 = __shfl(idreg, j + 4 + q);
      int s2 = __shfl(idreg, j + 8 + q);
      int s3 = __shfl(idreg, j + 12 + q);
      uint2 w0 = *(const uint2*)&gb4[s0 * 16 + kk];
      uint2 w1 = *(const uint2*)&gb4[s1 * 16 + kk];
      uint2 w2 = *(const uint2*)&gb4[s2 * 16 + kk];
      uint2 w3 = *(const uint2*)&gb4[s3 * 16 + kk];
      a0.x += __uint_as_float(w0.x << 16);
      a0.y += __uint_as_float(w0.x & 0xffff0000u);
      a0.z += __uint_as_float(w0.y << 16);
      a0.w += __uint_as_float(w0.y & 0xffff0000u);
      a1.x += __uint_as_float(w1.x << 16);
      a1.y += __uint_as_float(w1.x & 0xffff0000u);
      a1.z += __uint_as_float(w1.y << 16);
      a1.w += __uint_as_float(w1.y & 0xffff0000u);
      a2.x += __uint_as_float(w2.x << 16);
      a2.y += __uint_as_float(w2.x & 0xffff0000u);
      a2.z += __uint_as_float(w2.y << 16);
      a2.w += __uint_as_float(w2.y & 0xffff0000u);
      a3.x += __uint_as_float(w3.x << 16);
      a3.y += __uint_as_float(w3.x & 0xffff0000u);
      a3.z += __uint_as_float(w3.y << 16);
      a3.w += __uint_as_float(w3.y & 0xffff0000u);
    };

    int lim = min(deg, 64);
    for (int j = 0; j < lim; j += 16) proc16(idv, j);
    for (int base = 64; base < deg; base += 64) {          // rare overflow
      int id2 = (base + lane < deg) ? edge_src[off + base + lane] : SENT;
      int lim2 = min(64, deg - base);
      for (int j = 0; j < lim2; j += 16) proc16(id2, j);
    }

    float4 acc;
    acc.x = (a0.x + a1.x) + (a2.x + a3.x);
    acc.y = (a0.y + a1.y) + (a2.y + a3.y);
    acc.z = (a0.z + a1.z) + (a2.z + a3.z);
    acc.w = (a0.w + a1.w) + (a2.w + a3.w);
    acc.x += __shfl_xor(acc.x, 16); acc.x += __shfl_xor(acc.x, 32);
    acc.y += __shfl_xor(acc.y, 16); acc.y += __shfl_xor(acc.y, 32);
    acc.z += __shfl_xor(acc.z, 16); acc.z += __shfl_xor(acc.z, 32);
    acc.w += __shfl_xor(acc.w, 16); acc.w += __shfl_xor(acc.w, 32);

    if (q == 0) {                 // agg fragment: 8B per lane, swizzled
      unsigned swz = (unsigned)((r & 7) << 4);
      char* rowp = (char*)(myhl + r * 64);
      ushort4 pk;
      pk.x = f2bf(acc.x); pk.y = f2bf(acc.y);
      pk.z = f2bf(acc.z); pk.w = f2bf(acc.w);
      *(ushort4*)(rowp + ((8u * (unsigned)kk) ^ swz)) = pk;
    }
    idv = idnx;
  }

  // ---- W B-frags into registers ----
  bf16x8 wf[4][4];
#pragma unroll
  for (int kt = 0; kt < 4; ++kt)
#pragma unroll
    for (int jt = 0; jt < 4; ++jt)
      wf[kt][jt] =
          *(const bf16x8*)(wb + (jt * 16 + lrow) * 128 + kt * 32 + lkg * 8);

  f32x4 acc[4];
#pragma unroll
  for (int jt = 0; jt < 4; ++jt) acc[jt] = (f32x4){0.f, 0.f, 0.f, 0.f};

  // feat half (k 0..63): straight from global bf16 table
  int nrow = node0 + lrow;
  int nload = (nrow < n_nodes) ? nrow : n_nodes;   // sentinel row if OOB
#pragma unroll
  for (int kt = 0; kt < 2; ++kt) {
    bf16x8 af = *(const bf16x8*)((const unsigned short*)gb4 +
                                 (size_t)nload * DFEAT + kt * 32 + lkg * 8);
#pragma unroll
    for (int jt = 0; jt < 4; ++jt)
      acc[jt] = __builtin_amdgcn_mfma_f32_16x16x32_bf16(af, wf[kt][jt],
                                                        acc[jt], 0, 0, 0);
  }
  // agg half (k 64..127): from wave-private LDS (swizzled)
  unsigned aswz = (unsigned)((lrow & 7) << 4);
  const char* arow = (const char*)(myhl + lrow * 64);
#pragma unroll
  for (int kt = 2; kt < 4; ++kt) {
    bf16x8 af =
        *(const bf16x8*)(arow + ((unsigned)((kt - 2) * 64 + lkg * 16) ^ aswz));
#pragma unroll
    for (int jt = 0; jt < 4; ++jt)
      acc[jt] = __builtin_amdgcn_mfma_f32_16x16x32_bf16(af, wf[kt][jt],
                                                        acc[jt], 0, 0, 0);
  }

#pragma unroll
  for (int jt = 0; jt < 4; ++jt) {
    float bj = bias[jt * 16 + lrow];
#pragma unroll
    for (int r = 0; r < 4; ++r) {
      int n = node0 + lkg * 4 + r;
      if (n < n_nodes) out[n * DFEAT + jt * 16 + lrow] = acc[jt][r] + bj;
    }
  }
}

// ===========================================================================
// Last-resort fallback: atomic scatter + separate vector GEMM.
// ===========================================================================
__global__ __launch_bounds__(256) void gcn_scatter_kernel(
    const float4* __restrict__ feat4, const int* __restrict__ src,
    const int* __restrict__ dst, float* __restrict__ agg, int n_edges) {
  long long gid = (long long)blockIdx.x * blockDim.x + threadIdx.x;
  int e = (int)(gid >> 4);
  int c = (int)(gid & 15);
  if (e >= n_edges) return;
  float4 v = feat4[src[e] * 16 + c];
  float* p = agg + dst[e] * DFEAT + c * 4;
  atomicAdd(p + 0, v.x);
  atomicAdd(p + 1, v.y);
  atomicAdd(p + 2, v.z);
  atomicAdd(p + 3, v.w);
}

__global__ __launch_bounds__(256) void gcn_gemm_kernel(
    const float* __restrict__ feat, const float* __restrict__ agg,
    const float* __restrict__ W, const float* __restrict__ bias,
    float* __restrict__ out, int n_nodes) {
  __shared__ float4 Wl4[2048];
  __shared__ __align__(16) float hlf[16][128];
  int tid = threadIdx.x;
  for (int i = tid; i < 2048; i += 256) {
    int j = i >> 5, k4 = i & 31;
    Wl4[k4 * 64 + (j ^ (k4 & 7))] = ((const float4*)W)[i];
  }
  int node0 = blockIdx.x * 16;
  int wave = tid >> 6, lane = tid & 63;
  int mbase = wave * 4;
#pragma unroll
  for (int r = 0; r < 4; ++r) {
    int n = node0 + mbase + r;
    if (n < n_nodes) {
      hlf[mbase + r][lane]      = feat[n * DFEAT + lane];
      hlf[mbase + r][64 + lane] = agg[n * DFEAT + lane];
    }
  }
  __syncthreads();
  float a0 = 0.f, a1 = 0.f, a2 = 0.f, a3 = 0.f;
#pragma unroll 4
  for (int k4 = 0; k4 < 32; ++k4) {
    float4 w  = Wl4[k4 * 64 + (lane ^ (k4 & 7))];
    float4 h0 = *((const float4*)&hlf[mbase + 0][k4 * 4]);
    float4 h1 = *((const float4*)&hlf[mbase + 1][k4 * 4]);
    float4 h2 = *((const float4*)&hlf[mbase + 2][k4 * 4]);
    float4 h3 = *((const float4*)&hlf[mbase + 3][k4 * 4]);
    a0 += w.x * h0.x + w.y * h0.y + w.z * h0.z + w.w * h0.w;
    a1 += w.x * h1.x + w.y * h1.y + w.z * h1.z + w.w * h1.w;
    a2 += w.x * h2.x + w.y * h2.y + w.z * h2.z + w.w * h2.w;
    a3 += w.x * h3.x + w.y * h3.y + w.z * h3.z + w.w * h3.w;
  }
  float bj = bias[lane];
  int n = node0 + mbase;
  if (n + 0 < n_nodes) out[(n + 0) * DFEAT + lane] = a0 + bj;
  if (n + 1 < n_nodes) out[(n + 1) * DFEAT + lane] = a1 + bj;
  if (n + 2 < n_nodes) out[(n + 2) * DFEAT + lane] = a2 + bj;
  if (n + 3 < n_nodes) out[(n + 3) * DFEAT + lane] = a3 + bj;
}

// ===========================================================================

extern "C" void kernel_launch(void* const* d_in, const int* in_sizes, int n_in,
                              void* d_out, int out_size, void* d_ws, size_t ws_size,
                              hipStream_t stream) {
  const float* feat = (const float*)d_in[0];
  const int*   src  = (const int*)d_in[1];
  const int*   dst  = (const int*)d_in[2];
  const float* W    = (const float*)d_in[3];
  const float* bias = (const float*)d_in[4];
  float* out = (float*)d_out;

  int n_nodes = in_sizes[0] / DFEAT;   // 100000
  int n_edges = in_sizes[1];           // 1600000
  int nbkt = (n_nodes + BKSZ - 1) >> SB;   // 196

  auto align_up = [](size_t x) { return (x + 255) & ~(size_t)255; };
  size_t esrc_b = align_up((size_t)n_edges * 4);
  size_t off_b  = align_up((size_t)(n_nodes + 1) * 4);
  size_t bcnt_b = align_up((size_t)NBKT_PAD * 4);
  size_t bcur_b = align_up((size_t)NBKT_PAD * 4);
  size_t wb_b   = align_up((size_t)DFEAT * 128 * 2);
  size_t gb_b   = align_up((size_t)(n_nodes + 1) * DFEAT * 2);  // +sentinel
  size_t need   = esrc_b + off_b + bcnt_b + bcur_b + wb_b + gb_b;

  bool pairs_fit = (size_t)out_size * 4 >= (size_t)n_edges * 4;
  bool ok = pairs_fit && nbkt >= 1 && nbkt <= NBKT_PAD && ws_size >= need &&
            n_nodes < (1 << 23);

  if (ok) {
    char* p = (char*)d_ws;
    int* edge_src = (int*)p;   p += esrc_b;
    int* offsets  = (int*)p;   p += off_b;
    int* bcnt     = (int*)p;   p += bcnt_b;
    int* bcur     = (int*)p;   p += bcur_b;
    unsigned short* wb = (unsigned short*)p;   p += wb_b;
    unsigned short* gb = (unsigned short*)p;
    unsigned int* pairs = (unsigned int*)d_out;  // dead before out is written

    hipMemsetAsync(bcnt, 0, bcnt_b + bcur_b, stream);   // bcnt + bcur

    int n4 = n_nodes * (DFEAT / 4);
    int nw4 = DFEAT * 128 / 4;
    gcn_prep<<<1024, 256, 0, stream>>>(
        (const float4*)feat, (ushort4*)gb, n4,
        (const float4*)W, (ushort4*)wb, nw4,
        dst, bcnt, n_edges, nbkt);

    int pblocks = (n_edges + PLACE_CHUNK - 1) / PLACE_CHUNK;
    gcn_place<<<pblocks, 512, 0, stream>>>(src, dst, bcnt, bcur, pairs,
                                           n_edges, nbkt);

    gcn_fillk<<<nbkt, 512, 0, stream>>>(pairs, bcnt, offsets, edge_src,
                                        n_nodes, n_edges, nbkt);

    int gblocks = (n_nodes + 63) / 64;
    gcn_gather_mfma<<<gblocks, 256, 0, stream>>>(
        (const ushort4*)gb, wb, edge_src, offsets, bias, out, n_nodes);
  } else {
    size_t agg_bytes = (size_t)n_nodes * DFEAT * sizeof(float);
    float* agg = (ws_size >= agg_bytes) ? (float*)d_ws : out;
    hipMemsetAsync(agg, 0, agg_bytes, stream);
    long long st = (long long)n_edges * 16;
    gcn_scatter_kernel<<<(int)((st + 255) / 256), 256, 0, stream>>>(
        (const float4*)feat, src, dst, agg, n_edges);
    int gblocks = (n_nodes + 15) / 16;
    gcn_gemm_kernel<<<gblocks, 256, 0, stream>>>(feat, agg, W, bias, out,
                                                 n_nodes);
  }
}